// Round 7
// baseline (104.330 us; speedup 1.0000x reference)
//
#include <hip/hip_runtime.h>

#define KAPPA 0.276f
#define NTRI 8256        // 128*129/2 packed floats per batch
#define BATCH 1024
#define NBLK 2048        // 2 blocks per batch (row classes mod 8)
#define SCALE (1.0f / (128.0f * 1024.0f))   // /trace2(=128), /B for mean

__global__ __launch_bounds__(256) void trace_kernel(const float* __restrict__ net_out,
                                                    const float* __restrict__ U1,
                                                    float* __restrict__ ws,
                                                    float* __restrict__ out) {
    const int bid = blockIdx.x;
    const int b   = bid >> 1;
    const int tid = threadIdx.x;
    const int w   = tid >> 6;                 // wave 0..3
    const int l   = tid & 63;                 // lane owns elements k=l and k=l+64 of each row
    const int r   = ((bid & 1) << 2) + w;     // row class 0..7: rows r, r+8, ..., r+120

    unsigned int* cnt  = (unsigned int*)ws;   // counter in ws[0]
    float*        part = ws + 16;             // 2048 partials, separate cacheline

    const float* __restrict__ X = net_out + (size_t)b * NTRI;
    const float* __restrict__ U = U1 + (size_t)b * 128;

    // loop-invariant per-lane element offsets within a row
    const int kxl = l;
    const int kal = l + 16;
    const int kbl = (l & 0x70) | ((l + 2) & 15);
    const int kxh = l + 64;
    const int kah = (l + 80) & 127;
    const int kbh = ((l + 64) & 0x70) | ((l + 66) & 15);

    float sq = 0.f, hAl = 0.f, hBl = 0.f, hAh = 0.f, hBh = 0.f;

    // ---- rows i = r .. r+56 : only low half valid (k <= i < 64) ----
    {
        int i = r;
        int o = (r * (r + 1)) >> 1;
        #pragma unroll 4
        for (int t = 0; t < 8; ++t) {
            const float* __restrict__ R = X + o;
            float x  = R[kxl];
            float a  = R[kal];
            float bb = R[kbl];
            x  = (kxl <= i) ? x  : 0.f;
            a  = (kal <= i) ? a  : 0.f;
            bb = (kbl <= i) ? bb : 0.f;
            sq  = fmaf(x, x,  sq);
            hAl = fmaf(x, a,  hAl);
            hBl = fmaf(x, bb, hBl);
            o += (i << 3) + 36;
            i += 8;
        }
    }
    // ---- rows i = r+64 .. r+120 : both halves ----
    {
        int i = r + 64;
        int o = (i * (i + 1)) >> 1;
        #pragma unroll 4
        for (int t = 0; t < 8; ++t) {
            const float* __restrict__ R = X + o;
            float x  = R[kxl];           // k=l <= 63 < i: always valid
            float a  = R[kal];
            float bb = R[kbl];
            a = (kal <= i) ? a : 0.f;    // kbl <= 63 < i: always valid
            sq  = fmaf(x, x,  sq);
            hAl = fmaf(x, a,  hAl);
            hBl = fmaf(x, bb, hBl);

            float xh = R[kxh];
            float ah = R[kah];
            float bh = R[kbh];
            xh = (kxh <= i) ? xh : 0.f;
            ah = (kah <= i) ? ah : 0.f;
            bh = (kbh <= i) ? bh : 0.f;
            sq  = fmaf(xh, xh, sq);
            hAh = fmaf(xh, ah, hAh);
            hBh = fmaf(xh, bh, hBh);

            o += (i << 3) + 36;
            i += 8;
        }
    }

    // per-lane coefficients (site of element k is k>>1); HW cos, rel err ~1e-5
    const float m2k = -2.0f * KAPPA;
    const float cAl = m2k * __cosf(U[(l >> 1)]);
    const float cAh = m2k * __cosf(U[32 + (l >> 1)]);
    const float cBl = m2k * __cosf(U[64 + (l >> 1)]);
    const float cBh = m2k * __cosf(U[96 + (l >> 1)]);

    float val = sq + cAl * hAl + cAh * hAh + cBl * hBl + cBh * hBh;

    // wave reduce
    #pragma unroll
    for (int off = 32; off > 0; off >>= 1)
        val += __shfl_down(val, off, 64);

    __shared__ float red[4];
    __shared__ int   isLast;
    if (l == 0) red[w] = val;
    __syncthreads();

    if (tid == 0) {
        float p = red[0] + red[1] + red[2] + red[3];
        __hip_atomic_store(&part[bid], p, __ATOMIC_RELEASE, __HIP_MEMORY_SCOPE_AGENT);
        unsigned int old = __hip_atomic_fetch_add(cnt, 1u, __ATOMIC_ACQ_REL,
                                                  __HIP_MEMORY_SCOPE_AGENT);
        isLast = (old == NBLK - 1);
    }
    __syncthreads();

    // last block reduces all partials (agent-scope loads: bypass stale L2 lines)
    if (isLast) {
        float v = 0.f;
        #pragma unroll
        for (int m = 0; m < NBLK / 256; ++m)
            v += __hip_atomic_load(&part[tid + (m << 8)], __ATOMIC_RELAXED,
                                   __HIP_MEMORY_SCOPE_AGENT);
        #pragma unroll
        for (int off = 32; off > 0; off >>= 1)
            v += __shfl_down(v, off, 64);
        __syncthreads();              // red[] reuse
        if (l == 0) red[w] = v;
        __syncthreads();
        if (tid == 0)
            out[0] = (red[0] + red[1] + red[2] + red[3]) * SCALE;
    }
}

extern "C" void kernel_launch(void* const* d_in, const int* in_sizes, int n_in,
                              void* d_out, int out_size, void* d_ws, size_t ws_size,
                              hipStream_t stream) {
    const float* net_out = (const float*)d_in[0];  // (1024, 8256) fp32
    const float* U1      = (const float*)d_in[1];  // (1024, 2, 8, 8) fp32
    float* out = (float*)d_out;                    // scalar fp32
    float* ws  = (float*)d_ws;

    hipMemsetAsync(ws, 0, 4, stream);              // zero block counter
    trace_kernel<<<NBLK, 256, 0, stream>>>(net_out, U1, ws, out);
}